// Round 9
// baseline (141.440 us; speedup 1.0000x reference)
//
#include <hip/hip_runtime.h>

typedef unsigned short u16;
typedef short bf16x8 __attribute__((ext_vector_type(8)));
typedef float f32x4 __attribute__((ext_vector_type(4)));

#define BB 8
#define CC 768
#define NN 256
#define HH 12
#define DD 64
#define BCN 196608       // C*N per batch
#define SWS 589824       // 768*768 per batch
#define SCALE 0.125f
#define LDP 72           // LDS pitch (u16) for 64-wide tiles
#define LDPW 136         // LDS pitch (u16) for 128-wide tiles (272B rows: 16B-aligned, 2-way banks)

__device__ __forceinline__ u16 f2b(float f) {
    union { float f; unsigned int i; } v; v.f = f;
    unsigned int r = v.i + 0x7FFFu + ((v.i >> 16) & 1u);
    return (u16)(r >> 16);
}

// ---------------------------------------------------------------------------
// Algebra:
//   S = cross*cross^T (per batch), R = rowsums(cross)
//   G[dd][d] = SCALE*( sum_{j,c} Wp[d*12+j][c]*S[dd*12+j][c]
//                      + sum_j bp[d*12+j]*R[dd*12+j] )
//   U[m][dd] = sum_d xT[m][d]*G[dd][d]   (m = h*256+n)
//   out[b,o,n] = x + bd[o] + sum_c Wd[o][c]*U2[n][c]  (U2 = U flat [256][768])
// ---------------------------------------------------------------------------

// Dispatch 1: blk<144 -> S-tile (64x64, bf16; blk 0 zeros G[b]; diagonal tiles
// emit R). blk>=144 -> xT transpose tiles (48 per batch).
__global__ __launch_bounds__(256) void k_S(
    const float* __restrict__ cross, const float* __restrict__ x,
    u16* __restrict__ S, u16* __restrict__ xT,
    float* __restrict__ G, float* __restrict__ R)
{
    __shared__ __align__(16) u16 SMEM[2 * 64 * LDP];
    u16* As = SMEM;
    u16* Bs = SMEM + 64 * LDP;
    float (*T)[68] = reinterpret_cast<float(*)[68]>(SMEM);
    const int b = blockIdx.y, blk = blockIdx.x, t = threadIdx.x;
    const int lane = t & 63, wave = t >> 6;
    const int q = lane >> 4, tx = lane & 15;
    const int wm = (wave & 1) * 32, wn = (wave >> 1) * 32;

    if (blk < 144) {
        const int r0 = (blk / 12) * 64, c0 = (blk % 12) * 64;
        const float* crb = cross + b * BCN;
        f32x4 acc[2][2] = {};
        for (int k4 = 0; k4 < 4; ++k4) {
            const int nk = k4 * 64;
            {
                const int r = t >> 2, q4 = t & 3;
                const float* sa = crb + (r0 + r) * NN + nk;
                const float* sb = crb + (c0 + r) * NN + nk;
                u16* da = As + r * LDP;
                u16* db = Bs + r * LDP;
                #pragma unroll
                for (int u = 0; u < 4; ++u) {
                    const int cl = (q4 + 4 * u) * 4;
                    float4 va = *reinterpret_cast<const float4*>(sa + cl);
                    float4 vb = *reinterpret_cast<const float4*>(sb + cl);
                    ushort4 wa, wb;
                    wa.x = f2b(va.x); wa.y = f2b(va.y); wa.z = f2b(va.z); wa.w = f2b(va.w);
                    wb.x = f2b(vb.x); wb.y = f2b(vb.y); wb.z = f2b(vb.z); wb.w = f2b(vb.w);
                    *reinterpret_cast<ushort4*>(da + cl) = wa;
                    *reinterpret_cast<ushort4*>(db + cl) = wb;
                }
            }
            __syncthreads();
            #pragma unroll
            for (int kk = 0; kk < 2; ++kk) {
                bf16x8 a0 = *reinterpret_cast<bf16x8*>(As + (wm + tx) * LDP + kk * 32 + q * 8);
                bf16x8 a1 = *reinterpret_cast<bf16x8*>(As + (wm + 16 + tx) * LDP + kk * 32 + q * 8);
                bf16x8 b0 = *reinterpret_cast<bf16x8*>(Bs + (wn + tx) * LDP + kk * 32 + q * 8);
                bf16x8 b1 = *reinterpret_cast<bf16x8*>(Bs + (wn + 16 + tx) * LDP + kk * 32 + q * 8);
                acc[0][0] = __builtin_amdgcn_mfma_f32_16x16x32_bf16(a0, b0, acc[0][0], 0, 0, 0);
                acc[0][1] = __builtin_amdgcn_mfma_f32_16x16x32_bf16(a0, b1, acc[0][1], 0, 0, 0);
                acc[1][0] = __builtin_amdgcn_mfma_f32_16x16x32_bf16(a1, b0, acc[1][0], 0, 0, 0);
                acc[1][1] = __builtin_amdgcn_mfma_f32_16x16x32_bf16(a1, b1, acc[1][1], 0, 0, 0);
            }
            __syncthreads();
        }
        u16* Sb = S + b * SWS;
        #pragma unroll
        for (int i = 0; i < 2; ++i)
            #pragma unroll
            for (int j = 0; j < 2; ++j)
                #pragma unroll
                for (int r = 0; r < 4; ++r) {
                    const int row = r0 + wm + i * 16 + q * 4 + r;
                    const int col = c0 + wn + j * 16 + tx;
                    Sb[row * CC + col] = f2b(acc[i][j][r]);
                }
        if (blk == 0) {   // zero G[b]
            float4 z = {0.f, 0.f, 0.f, 0.f};
            float* Gb = G + b * 4096;
            #pragma unroll
            for (int u = 0; u < 4; ++u)
                *reinterpret_cast<float4*>(Gb + t * 16 + u * 4) = z;
        }
        if (r0 == c0) {   // R rows [r0, r0+64): exclusive ownership
            float* Rp = (float*)As;   // all LDS reads done (barrier above)
            const int row = t >> 2, seg = t & 3;
            const float* src = crb + (r0 + row) * NN + seg * 64;
            float s = 0.f;
            #pragma unroll
            for (int u = 0; u < 16; ++u) {
                float4 v = *reinterpret_cast<const float4*>(src + u * 4);
                s += v.x + v.y + v.z + v.w;
            }
            Rp[t] = s;
            __syncthreads();
            if (t < 64)
                R[b * CC + r0 + t] = Rp[t * 4] + Rp[t * 4 + 1] + Rp[t * 4 + 2] + Rp[t * 4 + 3];
        }
    } else {
        // xT tile: xT[(h*256+n)*64 + d] = x[b][(d*12+h)][n], bf16
        const int idx = blk - 144;
        const int m0 = idx * 64, h = m0 >> 8, nn0 = m0 & 255;
        const float* xb = x + b * BCN;
        {
            const int d = t >> 2, fq = t & 3;
            const float* src = xb + (d * HH + h) * NN + nn0;
            #pragma unroll
            for (int u = 0; u < 4; ++u) {
                const int nl = (fq + 4 * u) * 4;
                float4 v = *reinterpret_cast<const float4*>(src + nl);
                T[d][nl + 0] = v.x; T[d][nl + 1] = v.y; T[d][nl + 2] = v.z; T[d][nl + 3] = v.w;
            }
        }
        __syncthreads();
        {
            const int nn = t >> 2, dq = t & 3;
            u16* dst = xT + b * BCN + (m0 + nn) * DD;
            #pragma unroll
            for (int u = 0; u < 4; ++u) {
                const int d4 = (dq + 4 * u) * 4;
                ushort4 w;
                w.x = f2b(T[d4 + 0][nn]); w.y = f2b(T[d4 + 1][nn]);
                w.z = f2b(T[d4 + 2][nn]); w.w = f2b(T[d4 + 3][nn]);
                *reinterpret_cast<ushort4*>(dst + d4) = w;
            }
        }
    }
}

// Dispatch 2: G[dd][d] = SCALE*(Wp_flat[64][9216] . S_flat[64][9216]^T + bias)
// Split-K: 48 chunks (j in [0,12) x quarter in [0,4)), 3 iters of 64 each.
// Atomics into G (zeroed by k_S). Chunk 0 adds the bp.R bias term.
__global__ __launch_bounds__(256) void k_g(
    const float* __restrict__ Wp, const u16* __restrict__ S,
    const float* __restrict__ bp, const float* __restrict__ R,
    float* __restrict__ G)
{
    __shared__ __align__(16) u16 SMEM[2 * 64 * LDP];
    u16* As = SMEM;
    u16* Bs = SMEM + 64 * LDP;
    const int b = blockIdx.y, kc = blockIdx.x, t = threadIdx.x;
    const int j = kc >> 2, cb = (kc & 3) * 192;
    const int lane = t & 63, wave = t >> 6;
    const int q = lane >> 4, tx = lane & 15;
    const int wm = (wave & 1) * 32, wn = (wave >> 1) * 32;
    const u16* Sb = S + b * SWS;
    f32x4 acc[2][2] = {};
    for (int ii = 0; ii < 3; ++ii) {
        const int c0 = cb + ii * 64;
        {   // A[d][c] = Wp[d*12+j][c0+c]
            const int r = t >> 2, q4 = t & 3;
            const float* src = Wp + (r * HH + j) * CC + c0;
            u16* dst = As + r * LDP;
            #pragma unroll
            for (int u = 0; u < 4; ++u) {
                const int cl = (q4 + 4 * u) * 4;
                float4 v = *reinterpret_cast<const float4*>(src + cl);
                ushort4 w; w.x = f2b(v.x); w.y = f2b(v.y); w.z = f2b(v.z); w.w = f2b(v.w);
                *reinterpret_cast<ushort4*>(dst + cl) = w;
            }
        }
        {   // B[dd][c] = S[dd*12+j][c0+c]
            const int r = t >> 3, ch = (t & 7) * 8;
            *reinterpret_cast<uint4*>(Bs + r * LDP + ch) =
                *reinterpret_cast<const uint4*>(Sb + (r * HH + j) * CC + c0 + ch);
            *reinterpret_cast<uint4*>(Bs + (r + 32) * LDP + ch) =
                *reinterpret_cast<const uint4*>(Sb + ((r + 32) * HH + j) * CC + c0 + ch);
        }
        __syncthreads();
        #pragma unroll
        for (int kk = 0; kk < 2; ++kk) {
            bf16x8 a0 = *reinterpret_cast<bf16x8*>(As + (wm + tx) * LDP + kk * 32 + q * 8);
            bf16x8 a1 = *reinterpret_cast<bf16x8*>(As + (wm + 16 + tx) * LDP + kk * 32 + q * 8);
            bf16x8 b0 = *reinterpret_cast<bf16x8*>(Bs + (wn + tx) * LDP + kk * 32 + q * 8);
            bf16x8 b1 = *reinterpret_cast<bf16x8*>(Bs + (wn + 16 + tx) * LDP + kk * 32 + q * 8);
            acc[0][0] = __builtin_amdgcn_mfma_f32_16x16x32_bf16(a0, b0, acc[0][0], 0, 0, 0);
            acc[0][1] = __builtin_amdgcn_mfma_f32_16x16x32_bf16(a0, b1, acc[0][1], 0, 0, 0);
            acc[1][0] = __builtin_amdgcn_mfma_f32_16x16x32_bf16(a1, b0, acc[1][0], 0, 0, 0);
            acc[1][1] = __builtin_amdgcn_mfma_f32_16x16x32_bf16(a1, b1, acc[1][1], 0, 0, 0);
        }
        __syncthreads();
    }
    float* Gb = G + b * 4096;
    if (kc == 0) {
        float* bpf = (float*)As;        // 768 f32
        float* Rf  = bpf + CC;          // 768 f32
        #pragma unroll
        for (int u = 0; u < 3; ++u) {
            const int idx = t + u * 256;
            bpf[idx] = bp[idx];
            Rf[idx]  = R[b * CC + idx];
        }
        __syncthreads();
        #pragma unroll
        for (int i = 0; i < 2; ++i)
            #pragma unroll
            for (int j2 = 0; j2 < 2; ++j2)
                #pragma unroll
                for (int r = 0; r < 4; ++r) {
                    const int dI  = wm + i * 16 + q * 4 + r;    // A-row (d)
                    const int ddI = wn + j2 * 16 + tx;          // B-row (dd)
                    float bias = 0.f;
                    #pragma unroll
                    for (int jj = 0; jj < HH; ++jj)
                        bias += bpf[dI * HH + jj] * Rf[ddI * HH + jj];
                    atomicAdd(Gb + ddI * DD + dI, SCALE * (acc[i][j2][r] + bias));
                }
    } else {
        #pragma unroll
        for (int i = 0; i < 2; ++i)
            #pragma unroll
            for (int j2 = 0; j2 < 2; ++j2)
                #pragma unroll
                for (int r = 0; r < 4; ++r) {
                    const int dI  = wm + i * 16 + q * 4 + r;
                    const int ddI = wn + j2 * 16 + tx;
                    atomicAdd(Gb + ddI * DD + dI, SCALE * acc[i][j2][r]);
                }
    }
}

// Dispatch 3: blk<48 -> U[m][dd] = sum_d xT[m][d]*G[dd][d] (bf16 out);
// blk>=48 -> out init: out = x + bd[o]  (overwrites the 0xAA poison).
__global__ __launch_bounds__(256) void k_xm2(
    const u16* __restrict__ xT, const float* __restrict__ G,
    const float* __restrict__ x, const float* __restrict__ bd,
    u16* __restrict__ U, float* __restrict__ out)
{
    __shared__ __align__(16) u16 SMEM[2 * 64 * LDP];
    u16* As = SMEM;
    u16* Bs = SMEM + 64 * LDP;
    const int b = blockIdx.y, blk = blockIdx.x, t = threadIdx.x;
    if (blk < 48) {
        const int m0 = blk * 64;
        const int lane = t & 63, wave = t >> 6;
        const int q = lane >> 4, tx = lane & 15;
        const int wm = (wave & 1) * 32, wn = (wave >> 1) * 32;
        const u16* xTb = xT + b * BCN;
        const float* Gb = G + b * 4096;
        f32x4 acc[2][2] = {};
        {
            const int r = t >> 3, ch = (t & 7) * 8;
            *reinterpret_cast<uint4*>(As + r * LDP + ch) =
                *reinterpret_cast<const uint4*>(xTb + (m0 + r) * DD + ch);
            *reinterpret_cast<uint4*>(As + (r + 32) * LDP + ch) =
                *reinterpret_cast<const uint4*>(xTb + (m0 + r + 32) * DD + ch);
        }
        {
            const int r = t >> 2, q4 = t & 3;
            const float* src = Gb + r * DD;
            u16* dst = Bs + r * LDP;
            #pragma unroll
            for (int u = 0; u < 4; ++u) {
                const int cl = (q4 + 4 * u) * 4;
                float4 v = *reinterpret_cast<const float4*>(src + cl);
                ushort4 w; w.x = f2b(v.x); w.y = f2b(v.y); w.z = f2b(v.z); w.w = f2b(v.w);
                *reinterpret_cast<ushort4*>(dst + cl) = w;
            }
        }
        __syncthreads();
        #pragma unroll
        for (int kk = 0; kk < 2; ++kk) {
            bf16x8 a0 = *reinterpret_cast<bf16x8*>(As + (wm + tx) * LDP + kk * 32 + q * 8);
            bf16x8 a1 = *reinterpret_cast<bf16x8*>(As + (wm + 16 + tx) * LDP + kk * 32 + q * 8);
            bf16x8 b0 = *reinterpret_cast<bf16x8*>(Bs + (wn + tx) * LDP + kk * 32 + q * 8);
            bf16x8 b1 = *reinterpret_cast<bf16x8*>(Bs + (wn + 16 + tx) * LDP + kk * 32 + q * 8);
            acc[0][0] = __builtin_amdgcn_mfma_f32_16x16x32_bf16(a0, b0, acc[0][0], 0, 0, 0);
            acc[0][1] = __builtin_amdgcn_mfma_f32_16x16x32_bf16(a0, b1, acc[0][1], 0, 0, 0);
            acc[1][0] = __builtin_amdgcn_mfma_f32_16x16x32_bf16(a1, b0, acc[1][0], 0, 0, 0);
            acc[1][1] = __builtin_amdgcn_mfma_f32_16x16x32_bf16(a1, b1, acc[1][1], 0, 0, 0);
        }
        u16* Ub = U + b * BCN;
        #pragma unroll
        for (int i = 0; i < 2; ++i)
            #pragma unroll
            for (int j = 0; j < 2; ++j)
                #pragma unroll
                for (int r = 0; r < 4; ++r) {
                    const int m  = m0 + wm + i * 16 + q * 4 + r;
                    const int dd = wn + j * 16 + tx;
                    Ub[m * DD + dd] = f2b(acc[i][j][r]);
                }
    } else {
        const int idx = blk - 48;          // 4096 f32 per block
        const int base = b * BCN + idx * 4096 + t * 16;
        #pragma unroll
        for (int u = 0; u < 4; ++u) {
            const int off = idx * 4096 + t * 16 + u * 4;
            const int o = off >> 8;
            float4 v = *reinterpret_cast<const float4*>(x + base + u * 4);
            const float bb = bd[o];
            v.x += bb; v.y += bb; v.z += bb; v.w += bb;
            *reinterpret_cast<float4*>(out + base + u * 4) = v;
        }
    }
}

// Dispatch 4: out += Wd * U2^T. Split-K 2 x 384, BK=128 (3 iters, 6 barriers),
// f32 atomics into pre-inited out.
__global__ __launch_bounds__(256) void k_dep(
    const float* __restrict__ Wd, const u16* __restrict__ U, float* __restrict__ out)
{
    __shared__ __align__(16) u16 As[64 * LDPW];
    __shared__ __align__(16) u16 Bs[64 * LDPW];
    const int n0 = blockIdx.x * 64;
    const int o0 = blockIdx.y * 64;
    const int b  = blockIdx.z >> 1;
    const int cb = (blockIdx.z & 1) * 384;
    const int t = threadIdx.x;
    const int lane = t & 63, wave = t >> 6;
    const int q = lane >> 4, tx = lane & 15;
    const int wm = (wave & 1) * 32, wn = (wave >> 1) * 32;
    const u16* Ub = U + b * BCN;
    f32x4 acc[2][2] = {};
    for (int ii = 0; ii < 3; ++ii) {
        const int c0 = cb + ii * 128;
        {   // A: Wd[o0+r][c0..+128) f32->bf16
            const int r = t >> 2, q4 = t & 3;
            const float* src = Wd + (o0 + r) * CC + c0;
            u16* dst = As + r * LDPW;
            #pragma unroll
            for (int u = 0; u < 8; ++u) {
                const int cl = (q4 + 4 * u) * 4;
                float4 v = *reinterpret_cast<const float4*>(src + cl);
                ushort4 w; w.x = f2b(v.x); w.y = f2b(v.y); w.z = f2b(v.z); w.w = f2b(v.w);
                *reinterpret_cast<ushort4*>(dst + cl) = w;
            }
        }
        {   // B: U2[n0+r][c0..+128) bf16 copy
            const int r = t >> 2, ch8 = (t & 3) * 8;
            const u16* src = Ub + (n0 + r) * CC + c0;
            u16* dst = Bs + r * LDPW;
            #pragma unroll
            for (int u = 0; u < 4; ++u) {
                const int ch = (ch8 + 32 * u);
                *reinterpret_cast<uint4*>(dst + ch) =
                    *reinterpret_cast<const uint4*>(src + ch);
            }
        }
        __syncthreads();
        #pragma unroll
        for (int kk = 0; kk < 4; ++kk) {
            bf16x8 a0 = *reinterpret_cast<bf16x8*>(As + (wm + tx) * LDPW + kk * 32 + q * 8);
            bf16x8 a1 = *reinterpret_cast<bf16x8*>(As + (wm + 16 + tx) * LDPW + kk * 32 + q * 8);
            bf16x8 b0 = *reinterpret_cast<bf16x8*>(Bs + (wn + tx) * LDPW + kk * 32 + q * 8);
            bf16x8 b1 = *reinterpret_cast<bf16x8*>(Bs + (wn + 16 + tx) * LDPW + kk * 32 + q * 8);
            acc[0][0] = __builtin_amdgcn_mfma_f32_16x16x32_bf16(a0, b0, acc[0][0], 0, 0, 0);
            acc[0][1] = __builtin_amdgcn_mfma_f32_16x16x32_bf16(a0, b1, acc[0][1], 0, 0, 0);
            acc[1][0] = __builtin_amdgcn_mfma_f32_16x16x32_bf16(a1, b0, acc[1][0], 0, 0, 0);
            acc[1][1] = __builtin_amdgcn_mfma_f32_16x16x32_bf16(a1, b1, acc[1][1], 0, 0, 0);
        }
        __syncthreads();
    }
    #pragma unroll
    for (int i = 0; i < 2; ++i)
        #pragma unroll
        for (int j = 0; j < 2; ++j)
            #pragma unroll
            for (int r = 0; r < 4; ++r) {
                const int o = o0 + wm + i * 16 + q * 4 + r;
                const int n = n0 + wn + j * 16 + tx;
                atomicAdd(out + b * BCN + o * NN + n, acc[i][j][r]);
            }
}

extern "C" void kernel_launch(void* const* d_in, const int* in_sizes, int n_in,
                              void* d_out, int out_size, void* d_ws, size_t ws_size,
                              hipStream_t stream) {
    const float* x_ori = (const float*)d_in[0];
    const float* cross = (const float*)d_in[1];
    const float* Wp    = (const float*)d_in[2];
    const float* bp    = (const float*)d_in[3];
    const float* Wd    = (const float*)d_in[4];
    const float* bd    = (const float*)d_in[5];
    float* out = (float*)d_out;

    // ws layout (bytes): S bf16 [8][768][768] @0 (9.44 MB);
    // xT bf16 [8][3072][64] @9,437,184; U bf16 @12,582,912;
    // G f32 [8][64][64] @15,728,640; R f32 [8][768] @15,859,712.
    char* ws = (char*)d_ws;
    u16*   S  = (u16*)ws;
    u16*   xT = (u16*)(ws + 9437184);
    u16*   U  = (u16*)(ws + 12582912);
    float* G  = (float*)(ws + 15728640);
    float* R  = (float*)(ws + 15859712);

    k_S  <<<dim3(192, BB), 256, 0, stream>>>(cross, x_ori, S, xT, G, R);
    k_g  <<<dim3(48, BB), 256, 0, stream>>>(Wp, S, bp, R, G);
    k_xm2<<<dim3(96, BB), 256, 0, stream>>>(xT, G, x_ori, bd, U, out);
    k_dep<<<dim3(4, 12, 16), 256, 0, stream>>>(Wd, U, out);
}

// Round 10
// 125.277 us; speedup vs baseline: 1.1290x; 1.1290x over previous
//
#include <hip/hip_runtime.h>

typedef unsigned short u16;
typedef short bf16x8 __attribute__((ext_vector_type(8)));
typedef float f32x4 __attribute__((ext_vector_type(4)));

#define BB 8
#define CC 768
#define NN 256
#define HH 12
#define DD 64
#define K3 3072          // H*N
#define BCN 196608       // C*N per batch
#define SCALE 0.125f
#define LDP 72           // LDS pitch (u16): 144B rows, 16B-aligned, 2-way banks only

__device__ __forceinline__ u16 f2b(float f) {
    union { float f; unsigned int i; } v; v.f = f;
    unsigned int r = v.i + 0x7FFFu + ((v.i >> 16) & 1u);
    return (u16)(r >> 16);
}

// ---------------------------------------------------------------------------
// Stage 1: cp[b,o,n] = sum_c Wp[o,c]*cross[b,c,n] + bp[o]     (bf16 out)
// NT-MFMA 64x64x64 tiles. B-tile (cross^T) built in-kernel: coalesced f32
// loads into LDS tile T, transposed+cvt re-read into Bs. Blocks (0,0,b) also
// zero G[b] (consumed by k_gram next dispatch — stream-ordered).
// ---------------------------------------------------------------------------
__global__ __launch_bounds__(256) void k_proj(
    const float* __restrict__ Wp, const float* __restrict__ cross,
    const float* __restrict__ bp, u16* __restrict__ cp, float* __restrict__ G)
{
    __shared__ __align__(16) u16 As[64 * LDP];
    __shared__ __align__(16) u16 Bs[64 * LDP];
    __shared__ __align__(16) float T[64][68];
    const int n0 = blockIdx.x * 64;
    const int o0 = blockIdx.y * 64;
    const int b  = blockIdx.z;
    const int t = threadIdx.x;
    const int lane = t & 63, wave = t >> 6;
    const int q = lane >> 4, tx = lane & 15;
    const int wm = (wave & 1) * 32, wn = (wave >> 1) * 32;

    if (blockIdx.x == 0 && blockIdx.y == 0) {   // zero G[b]
        float4 z = {0.f, 0.f, 0.f, 0.f};
        float* Gb = G + b * 4096;
        #pragma unroll
        for (int j = 0; j < 4; ++j)
            *reinterpret_cast<float4*>(Gb + t * 4 + j * 1024) = z;
    }

    const float* crb = cross + b * BCN;
    f32x4 acc[2][2] = {};
    for (int c0 = 0; c0 < CC; c0 += 64) {
        {   // A: Wp[o0+r][c0..+64) f32->bf16
            const int r = t >> 2, cq = t & 3;
            const float* src = Wp + (o0 + r) * CC + c0;
            u16* dst = As + r * LDP;
            #pragma unroll
            for (int u = 0; u < 4; ++u) {
                const int cl = (cq + 4 * u) * 4;
                float4 v = *reinterpret_cast<const float4*>(src + cl);
                ushort4 w; w.x = f2b(v.x); w.y = f2b(v.y); w.z = f2b(v.z); w.w = f2b(v.w);
                *reinterpret_cast<ushort4*>(dst + cl) = w;
            }
        }
        {   // T: cross[c0+r][n0..+64) coalesced f32
            const int r = t >> 2, fq = t & 3;
            const float* src = crb + (c0 + r) * NN + n0;
            #pragma unroll
            for (int u = 0; u < 4; ++u) {
                const int nl = (fq + 4 * u) * 4;
                float4 v = *reinterpret_cast<const float4*>(src + nl);
                T[r][nl + 0] = v.x; T[r][nl + 1] = v.y; T[r][nl + 2] = v.z; T[r][nl + 3] = v.w;
            }
        }
        __syncthreads();
        {   // Bs[n][c] = cvt(T[c][n])  (transpose; T col reads are 2-way = free)
            const int nn = t >> 2, cq = t & 3;
            u16* dst = Bs + nn * LDP;
            #pragma unroll
            for (int u = 0; u < 4; ++u) {
                const int c4 = (cq + 4 * u) * 4;
                ushort4 w;
                w.x = f2b(T[c4 + 0][nn]); w.y = f2b(T[c4 + 1][nn]);
                w.z = f2b(T[c4 + 2][nn]); w.w = f2b(T[c4 + 3][nn]);
                *reinterpret_cast<ushort4*>(dst + c4) = w;
            }
        }
        __syncthreads();
        #pragma unroll
        for (int kk = 0; kk < 2; ++kk) {
            bf16x8 a0 = *reinterpret_cast<bf16x8*>(As + (wm + tx) * LDP + kk * 32 + q * 8);
            bf16x8 a1 = *reinterpret_cast<bf16x8*>(As + (wm + 16 + tx) * LDP + kk * 32 + q * 8);
            bf16x8 b0 = *reinterpret_cast<bf16x8*>(Bs + (wn + tx) * LDP + kk * 32 + q * 8);
            bf16x8 b1 = *reinterpret_cast<bf16x8*>(Bs + (wn + 16 + tx) * LDP + kk * 32 + q * 8);
            acc[0][0] = __builtin_amdgcn_mfma_f32_16x16x32_bf16(a0, b0, acc[0][0], 0, 0, 0);
            acc[0][1] = __builtin_amdgcn_mfma_f32_16x16x32_bf16(a0, b1, acc[0][1], 0, 0, 0);
            acc[1][0] = __builtin_amdgcn_mfma_f32_16x16x32_bf16(a1, b0, acc[1][0], 0, 0, 0);
            acc[1][1] = __builtin_amdgcn_mfma_f32_16x16x32_bf16(a1, b1, acc[1][1], 0, 0, 0);
        }
        __syncthreads();
    }
    u16* cpb = cp + b * BCN;
    #pragma unroll
    for (int i = 0; i < 2; ++i)
        #pragma unroll
        for (int j = 0; j < 2; ++j)
            #pragma unroll
            for (int r = 0; r < 4; ++r) {
                const int o = o0 + wm + i * 16 + q * 4 + r;
                const int n = n0 + wn + j * 16 + tx;
                cpb[o * NN + n] = f2b(acc[i][j][r] + bp[o]);
            }
}

// ---------------------------------------------------------------------------
// Stage 2: G[b][dd][d] += SCALE * sum_k cross_view[dd][k]*cp_view[d][k]
// Split-K 48 x 64 chunks, f32 atomics (G pre-zeroed by k_proj).
// ---------------------------------------------------------------------------
__global__ __launch_bounds__(256) void k_gram(
    const float* __restrict__ cross, const u16* __restrict__ cp, float* __restrict__ G)
{
    __shared__ __align__(16) u16 As[64 * LDP];
    __shared__ __align__(16) u16 Bs[64 * LDP];
    const int kb = blockIdx.x * 64;
    const int b  = blockIdx.y;
    const int t = threadIdx.x;
    const int lane = t & 63, wave = t >> 6;
    const int q = lane >> 4, tx = lane & 15;
    const int wm = (wave & 1) * 32, wn = (wave >> 1) * 32;
    const float* crb = cross + b * BCN;
    const u16* cpb = cp + b * BCN;
    f32x4 acc[2][2] = {};
    {
        const int r = t >> 2, cq = t & 3;
        const float* src = crb + r * K3 + kb;
        u16* dst = As + r * LDP;
        #pragma unroll
        for (int u = 0; u < 4; ++u) {
            const int cl = (cq + 4 * u) * 4;
            float4 v = *reinterpret_cast<const float4*>(src + cl);
            ushort4 w; w.x = f2b(v.x); w.y = f2b(v.y); w.z = f2b(v.z); w.w = f2b(v.w);
            *reinterpret_cast<ushort4*>(dst + cl) = w;
        }
    }
    {
        const int r = t >> 3, ch = (t & 7) * 8;
        *reinterpret_cast<uint4*>(Bs + r * LDP + ch) =
            *reinterpret_cast<const uint4*>(cpb + r * K3 + kb + ch);
        *reinterpret_cast<uint4*>(Bs + (r + 32) * LDP + ch) =
            *reinterpret_cast<const uint4*>(cpb + (r + 32) * K3 + kb + ch);
    }
    __syncthreads();
    #pragma unroll
    for (int kk = 0; kk < 2; ++kk) {
        bf16x8 a0 = *reinterpret_cast<bf16x8*>(As + (wm + tx) * LDP + kk * 32 + q * 8);
        bf16x8 a1 = *reinterpret_cast<bf16x8*>(As + (wm + 16 + tx) * LDP + kk * 32 + q * 8);
        bf16x8 b0 = *reinterpret_cast<bf16x8*>(Bs + (wn + tx) * LDP + kk * 32 + q * 8);
        bf16x8 b1 = *reinterpret_cast<bf16x8*>(Bs + (wn + 16 + tx) * LDP + kk * 32 + q * 8);
        acc[0][0] = __builtin_amdgcn_mfma_f32_16x16x32_bf16(a0, b0, acc[0][0], 0, 0, 0);
        acc[0][1] = __builtin_amdgcn_mfma_f32_16x16x32_bf16(a0, b1, acc[0][1], 0, 0, 0);
        acc[1][0] = __builtin_amdgcn_mfma_f32_16x16x32_bf16(a1, b0, acc[1][0], 0, 0, 0);
        acc[1][1] = __builtin_amdgcn_mfma_f32_16x16x32_bf16(a1, b1, acc[1][1], 0, 0, 0);
    }
    float* Gb = G + b * 4096;
    #pragma unroll
    for (int i = 0; i < 2; ++i)
        #pragma unroll
        for (int j = 0; j < 2; ++j)
            #pragma unroll
            for (int r = 0; r < 4; ++r) {
                const int dd = wm + i * 16 + q * 4 + r;
                const int d  = wn + j * 16 + tx;
                atomicAdd(Gb + dd * DD + d, acc[i][j][r] * SCALE);
            }
}

// ---------------------------------------------------------------------------
// Stage 3: U[b][m][dd] = sum_d xT[m][d]*G[dd][d].  A-tile (x^T) built
// in-kernel via LDS f32 tile T. U (bf16) aliases cp. 48 m-tiles x 8 batches.
// ---------------------------------------------------------------------------
__global__ __launch_bounds__(256) void k_xm(
    const float* __restrict__ x, const float* __restrict__ G, u16* __restrict__ U)
{
    __shared__ __align__(16) u16 As[64 * LDP];
    __shared__ __align__(16) u16 Bs[64 * LDP];
    __shared__ __align__(16) float T[64][68];
    const int m0 = blockIdx.x * 64;
    const int b  = blockIdx.y;
    const int h   = m0 >> 8;       // head index (m = h*256 + nn)
    const int nn0 = m0 & 255;
    const int t = threadIdx.x;
    const int lane = t & 63, wave = t >> 6;
    const int q = lane >> 4, tx = lane & 15;
    const int wm = (wave & 1) * 32, wn = (wave >> 1) * 32;
    const float* xb = x + b * BCN;
    const float* Gb = G + b * 4096;
    f32x4 acc[2][2] = {};
    {   // T[d][nl] = x[(d*12+h)*256 + nn0+nl]  (coalesced rows)
        const int d = t >> 2, fq = t & 3;
        const float* src = xb + (d * HH + h) * NN + nn0;
        #pragma unroll
        for (int u = 0; u < 4; ++u) {
            const int nl = (fq + 4 * u) * 4;
            float4 v = *reinterpret_cast<const float4*>(src + nl);
            T[d][nl + 0] = v.x; T[d][nl + 1] = v.y; T[d][nl + 2] = v.z; T[d][nl + 3] = v.w;
        }
    }
    {   // Bs[dd][d] = cvt(G[dd][d])
        const int r = t >> 2, cq = t & 3;
        const float* src = Gb + r * DD;
        u16* dst = Bs + r * LDP;
        #pragma unroll
        for (int u = 0; u < 4; ++u) {
            const int cl = (cq + 4 * u) * 4;
            float4 v = *reinterpret_cast<const float4*>(src + cl);
            ushort4 w; w.x = f2b(v.x); w.y = f2b(v.y); w.z = f2b(v.z); w.w = f2b(v.w);
            *reinterpret_cast<ushort4*>(dst + cl) = w;
        }
    }
    __syncthreads();
    {   // As[m_local][d] = cvt(T[d][m_local])  (transpose)
        const int nn = t >> 2, dq = t & 3;
        u16* dst = As + nn * LDP;
        #pragma unroll
        for (int u = 0; u < 4; ++u) {
            const int d4 = (dq + 4 * u) * 4;
            ushort4 w;
            w.x = f2b(T[d4 + 0][nn]); w.y = f2b(T[d4 + 1][nn]);
            w.z = f2b(T[d4 + 2][nn]); w.w = f2b(T[d4 + 3][nn]);
            *reinterpret_cast<ushort4*>(dst + d4) = w;
        }
    }
    __syncthreads();
    #pragma unroll
    for (int kk = 0; kk < 2; ++kk) {
        bf16x8 a0 = *reinterpret_cast<bf16x8*>(As + (wm + tx) * LDP + kk * 32 + q * 8);
        bf16x8 a1 = *reinterpret_cast<bf16x8*>(As + (wm + 16 + tx) * LDP + kk * 32 + q * 8);
        bf16x8 b0 = *reinterpret_cast<bf16x8*>(Bs + (wn + tx) * LDP + kk * 32 + q * 8);
        bf16x8 b1 = *reinterpret_cast<bf16x8*>(Bs + (wn + 16 + tx) * LDP + kk * 32 + q * 8);
        acc[0][0] = __builtin_amdgcn_mfma_f32_16x16x32_bf16(a0, b0, acc[0][0], 0, 0, 0);
        acc[0][1] = __builtin_amdgcn_mfma_f32_16x16x32_bf16(a0, b1, acc[0][1], 0, 0, 0);
        acc[1][0] = __builtin_amdgcn_mfma_f32_16x16x32_bf16(a1, b0, acc[1][0], 0, 0, 0);
        acc[1][1] = __builtin_amdgcn_mfma_f32_16x16x32_bf16(a1, b1, acc[1][1], 0, 0, 0);
    }
    u16* Ub = U + b * BCN;
    #pragma unroll
    for (int i = 0; i < 2; ++i)
        #pragma unroll
        for (int j = 0; j < 2; ++j)
            #pragma unroll
            for (int r = 0; r < 4; ++r) {
                const int m  = m0 + wm + i * 16 + q * 4 + r;
                const int dd = wn + j * 16 + tx;
                Ub[m * DD + dd] = f2b(acc[i][j][r]);
            }
}

// ---------------------------------------------------------------------------
// Stage 4: out[b,o,n] = x[b,o,n] + bd[o] + sum_k Wd[o,k]*U2[n,k]
// A=Wd (f32 cvt), B=U2 = U flat viewed [256][768] (bf16, k-contig). Native NT.
// ---------------------------------------------------------------------------
__global__ __launch_bounds__(256) void k_dep(
    const float* __restrict__ Wd, const u16* __restrict__ U,
    const float* __restrict__ bd, const float* __restrict__ x, float* __restrict__ out)
{
    __shared__ __align__(16) u16 As[64 * LDP];
    __shared__ __align__(16) u16 Bs[64 * LDP];
    const int n0 = blockIdx.x * 64;
    const int o0 = blockIdx.y * 64;
    const int b  = blockIdx.z;
    const int t = threadIdx.x;
    const int lane = t & 63, wave = t >> 6;
    const int q = lane >> 4, tx = lane & 15;
    const int wm = (wave & 1) * 32, wn = (wave >> 1) * 32;
    const u16* Ub = U + b * BCN;
    f32x4 acc[2][2] = {};
    for (int c0 = 0; c0 < CC; c0 += 64) {
        {
            const int r = t >> 2, cq = t & 3;
            const float* src = Wd + (o0 + r) * CC + c0;
            u16* dst = As + r * LDP;
            #pragma unroll
            for (int u = 0; u < 4; ++u) {
                const int cl = (cq + 4 * u) * 4;
                float4 v = *reinterpret_cast<const float4*>(src + cl);
                ushort4 w; w.x = f2b(v.x); w.y = f2b(v.y); w.z = f2b(v.z); w.w = f2b(v.w);
                *reinterpret_cast<ushort4*>(dst + cl) = w;
            }
        }
        {
            const int r = t >> 3, ch = (t & 7) * 8;
            *reinterpret_cast<uint4*>(Bs + r * LDP + ch) =
                *reinterpret_cast<const uint4*>(Ub + (n0 + r) * CC + c0 + ch);
            *reinterpret_cast<uint4*>(Bs + (r + 32) * LDP + ch) =
                *reinterpret_cast<const uint4*>(Ub + (n0 + r + 32) * CC + c0 + ch);
        }
        __syncthreads();
        #pragma unroll
        for (int kk = 0; kk < 2; ++kk) {
            bf16x8 a0 = *reinterpret_cast<bf16x8*>(As + (wm + tx) * LDP + kk * 32 + q * 8);
            bf16x8 a1 = *reinterpret_cast<bf16x8*>(As + (wm + 16 + tx) * LDP + kk * 32 + q * 8);
            bf16x8 b0 = *reinterpret_cast<bf16x8*>(Bs + (wn + tx) * LDP + kk * 32 + q * 8);
            bf16x8 b1 = *reinterpret_cast<bf16x8*>(Bs + (wn + 16 + tx) * LDP + kk * 32 + q * 8);
            acc[0][0] = __builtin_amdgcn_mfma_f32_16x16x32_bf16(a0, b0, acc[0][0], 0, 0, 0);
            acc[0][1] = __builtin_amdgcn_mfma_f32_16x16x32_bf16(a0, b1, acc[0][1], 0, 0, 0);
            acc[1][0] = __builtin_amdgcn_mfma_f32_16x16x32_bf16(a1, b0, acc[1][0], 0, 0, 0);
            acc[1][1] = __builtin_amdgcn_mfma_f32_16x16x32_bf16(a1, b1, acc[1][1], 0, 0, 0);
        }
        __syncthreads();
    }
    #pragma unroll
    for (int i = 0; i < 2; ++i)
        #pragma unroll
        for (int j = 0; j < 2; ++j)
            #pragma unroll
            for (int r = 0; r < 4; ++r) {
                const int o = o0 + wm + i * 16 + q * 4 + r;
                const int n = n0 + wn + j * 16 + tx;
                const int idx = b * BCN + o * NN + n;
                out[idx] = acc[i][j][r] + bd[o] + x[idx];
            }
}

extern "C" void kernel_launch(void* const* d_in, const int* in_sizes, int n_in,
                              void* d_out, int out_size, void* d_ws, size_t ws_size,
                              hipStream_t stream) {
    const float* x_ori = (const float*)d_in[0];
    const float* cross = (const float*)d_in[1];
    const float* Wp    = (const float*)d_in[2];
    const float* bp    = (const float*)d_in[3];
    const float* Wd    = (const float*)d_in[4];
    const float* bd    = (const float*)d_in[5];
    float* out = (float*)d_out;

    // ws: [0, 3,145,728): cp bf16 [8][768][256]; ALIASED by U bf16
    //     [8][3072][64] after k_gram (cp dead, stream-serialized).
    //     [3,145,728, +131,072): G f32 [8][64][64] (zeroed by k_proj blocks).
    u16*   cp = (u16*)d_ws;
    u16*   U  = (u16*)d_ws;
    float* G  = (float*)((char*)d_ws + (size_t)BB * BCN * sizeof(u16));

    k_proj<<<dim3(4, 12, BB), 256, 0, stream>>>(Wp, cross, bp, cp, G);
    k_gram<<<dim3(48, BB), 256, 0, stream>>>(cross, cp, G);
    k_xm  <<<dim3(48, BB), 256, 0, stream>>>(x_ori, G, U);
    k_dep <<<dim3(4, 12, BB), 256, 0, stream>>>(Wd, U, bd, x_ori, out);
}